// Round 6
// baseline (219.078 us; speedup 1.0000x reference)
//
#include <hip/hip_runtime.h>
#include <hip/hip_cooperative_groups.h>
#include <math.h>

namespace cg = cooperative_groups;

#define BN 8192
#define DN 512
#define KN 8
#define WIN 16          // window half-width around sorted position (>= KN, margin)

typedef unsigned long long u64;
typedef unsigned int u32;

// ---- ws layout (bytes) ----
// keys0     : u64  [8192] @ 0
// keys1     : u64  [8192] @ 65536
// sortedIdx : int  [8192] @ 131072
// sortedLab : float[8192] @ 163840
// partials  : float[256]  @ 196608
#define OFF_K0    0
#define OFF_K1    65536
#define OFF_SIDX  131072
#define OFF_SLAB  163840
#define OFF_PART  196608

// Order-preserving float->uint transform (all floats).
__device__ __forceinline__ u32 flip_f32(u32 f) {
  return f ^ (u32)(((int)f >> 31) | 0x80000000);
}

__device__ __forceinline__ u64 shfl_xor_u64(u64 v, int mask) {
  u32 lo = (u32)v, hi = (u32)(v >> 32);
  lo = (u32)__shfl_xor((int)lo, mask, 64);
  hi = (u32)__shfl_xor((int)hi, mask, 64);
  return ((u64)hi << 32) | lo;
}

// Merge-path level inside LDS: in has sorted runs of length R (power of 2),
// out gets runs of 2R. 1024 elements, 512 threads -> 2 outputs/thread.
__device__ __forceinline__ void lds_merge(const u64* in, u64* out, int R, int tid) {
  for (int o = tid; o < 1024; o += 512) {
    int off = o & (2 * R - 1);
    const u64* A = in + (o - off);
    const u64* B = A + R;
    int lo = off > R ? off - R : 0;
    int hi = off < R ? off : R;
    while (lo < hi) {
      int m = (lo + hi) >> 1;
      if (A[m] < B[off - m - 1]) lo = m + 1; else hi = m;
    }
    int a = lo, b = off - lo;
    u64 va = (a < R) ? A[a] : ~0ull;
    u64 vb = (b < R) ? B[b] : ~0ull;
    out[o] = va < vb ? va : vb;
  }
}

// Global merge-path pass, runs RUN -> 2*RUN. One thread per output t<8192.
template <int RUN, bool FINAL>
__device__ __forceinline__ void merge_device(const u64* __restrict__ in,
                                             u64* __restrict__ outk,
                                             int* __restrict__ sIdx,
                                             float* __restrict__ sLab,
                                             int t) {
  if (t < BN) {
    const int seg = t / (2 * RUN);
    const int o   = t & (2 * RUN - 1);
    const u64* A = in + seg * 2 * RUN;
    const u64* B = A + RUN;

    int lo = (o > RUN) ? (o - RUN) : 0;
    int hi = (o < RUN) ? o : RUN;
    while (lo < hi) {
      int a = (lo + hi) >> 1;
      if (A[a] < B[o - a - 1]) lo = a + 1; else hi = a;
    }
    const int a = lo, b = o - a;
    u64 va = (a < RUN) ? A[a] : ~0ull;
    u64 vb = (b < RUN) ? B[b] : ~0ull;
    u64 v = (va < vb) ? va : vb;

    if (FINAL) {
      u32 f = (u32)(v >> 32);
      u32 orig = (f & 0x80000000u) ? (f ^ 0x80000000u) : ~f;  // unflip
      sIdx[t] = (int)(u32)v;
      sLab[t] = __uint_as_float(orig);
    } else {
      outk[t] = v;
    }
  }
}

// ---------------------------------------------------------------------------
// Single cooperative kernel: 256 blocks x 512 threads (1 block/CU).
// P1 chunk sort -> P2..P4 merge passes -> P5 select+gather+cosine -> P6 reduce
// ---------------------------------------------------------------------------
__global__ __launch_bounds__(512, 2) void fused_kernel(const float* __restrict__ S,
                                                       const float* __restrict__ L,
                                                       u64* __restrict__ keys0,
                                                       u64* __restrict__ keys1,
                                                       int* __restrict__ sortedIdx,
                                                       float* __restrict__ sortedLab,
                                                       float* __restrict__ partials,
                                                       float* __restrict__ out) {
  cg::grid_group grid = cg::this_grid();
  const int tid  = threadIdx.x;      // 0..511
  const int lane = tid & 63;
  const int wv   = tid >> 6;         // 0..7
  const int blk  = blockIdx.x;       // 0..255

  __shared__ u64 bufA[1024];
  __shared__ u64 bufB[1024];

  // ---- P1: blocks 0..7 each sort a 1024-key chunk (wave reg-sort 128 +
  //      3 LDS merge-path levels). Proven R5 sort1 body. ----
  if (blk < 8) {
    const int base = blk * 1024 + wv * 128;
    const int g0 = base + lane, g1 = base + 64 + lane;
    u64 v0 = ((u64)flip_f32(__float_as_uint(L[g0])) << 32) | (u32)g0;
    u64 v1 = ((u64)flip_f32(__float_as_uint(L[g1])) << 32) | (u32)g1;

#pragma unroll
    for (int k = 2; k <= 128; k <<= 1) {
#pragma unroll
      for (int j = 64; j > 0; j >>= 1) {
        if (j >= k) continue;
        if (j == 64) {                       // k==128: cross-reg, ascending
          u64 mn = v0 < v1 ? v0 : v1;
          u64 mx = v0 < v1 ? v1 : v0;
          v0 = mn; v1 = mx;
        } else {
          u64 o0 = shfl_xor_u64(v0, j);
          u64 o1 = shfl_xor_u64(v1, j);
          bool lower = (lane & j) == 0;
          bool up0, up1;
          if (k == 128)     { up0 = true;  up1 = true;  }
          else if (k == 64) { up0 = true;  up1 = false; }
          else { bool u = (lane & k) == 0; up0 = u; up1 = u; }
          bool t0 = (up0 == lower), t1 = (up1 == lower);
          v0 = t0 ? (v0 < o0 ? v0 : o0) : (v0 < o0 ? o0 : v0);
          v1 = t1 ? (v1 < o1 ? v1 : o1) : (v1 < o1 ? o1 : v1);
        }
      }
    }

    bufA[wv * 128 + lane]      = v0;
    bufA[wv * 128 + 64 + lane] = v1;
    __syncthreads();
    lds_merge(bufA, bufB, 128, tid); __syncthreads();
    lds_merge(bufB, bufA, 256, tid); __syncthreads();
    lds_merge(bufA, bufB, 512, tid); __syncthreads();

    keys0[blk * 1024 + tid]       = bufB[tid];
    keys0[blk * 1024 + 512 + tid] = bufB[512 + tid];
  }
  grid.sync();

  // ---- P2..P4: global merge-path passes (blocks 0..15 carry the work) ----
  const int t = blk * 512 + tid;
  merge_device<1024, false>(keys0, keys1, nullptr, nullptr, t);
  grid.sync();
  merge_device<2048, false>(keys1, keys0, nullptr, nullptr, t);
  grid.sync();
  merge_device<4096, true >(keys0, nullptr, sortedIdx, sortedLab, t);
  grid.sync();

  // ---- P5: one wave per 4 sorted rows; XCD-swizzled contiguous spans ----
  const int xcd  = blk & 7;
  const int span = blk >> 3;                       // 0..31
  float wavesim = 0.0f;

  for (int r = 0; r < 4; ++r) {
    const int p  = xcd * 1024 + span * 32 + wv * 4 + r;   // sorted position
    const int b  = sortedIdx[p];                          // original row
    const float Lb = sortedLab[p];

    // selection: lanes 0..32 hold window candidates
    u64 key = ~0ull;
    {
      int q = p - WIN + lane;
      if (lane <= 2 * WIN && q >= 0 && q < BN) {
        float dist = fabsf(sortedLab[q] - Lb);     // >=0: IEEE bits order-preserving
        key = ((u64)__float_as_uint(dist) << 32) | (u32)sortedIdx[q];
      }
    }
    // 64-lane bitonic sort ascending (21 substeps)
#pragma unroll
    for (int k = 2; k <= 64; k <<= 1) {
#pragma unroll
      for (int j = 32; j > 0; j >>= 1) {
        if (j >= k) continue;
        u64 o = shfl_xor_u64(key, j);
        bool lower = (lane & j) == 0;
        bool up = (k == 64) ? true : ((lane & k) == 0);
        key = (up == lower) ? (key < o ? key : o) : (key < o ? o : key);
      }
    }
    // lanes 0..7 hold the 8 nearest; normalized Gaussian weights
    float e = 0.0f;
    if (lane < 8) {
      float d = __uint_as_float((u32)(key >> 32));
      e = expf(-d * d * (1.0f / 50.0f));           // 2*STD^2 = 50; const cancels
    }
    float ssum = e;
    ssum += __shfl_xor(ssum, 1, 64);
    ssum += __shfl_xor(ssum, 2, 64);
    ssum += __shfl_xor(ssum, 4, 64);
    float wn = e / ssum;

    int ix[KN]; float w[KN];
    int myidx = (int)(u32)key;
#pragma unroll
    for (int k = 0; k < KN; k++) {
      ix[k] = __shfl(myidx, k, 64);
      w[k]  = __shfl(wn,    k, 64);
    }

    // gather + weighted mean + cosine
    const float4* Srow = (const float4*)(S + (size_t)b * DN);
    float4 s0 = Srow[lane];
    float4 s1 = Srow[lane + 64];

    float4 m0 = make_float4(0.f, 0.f, 0.f, 0.f);
    float4 m1 = make_float4(0.f, 0.f, 0.f, 0.f);
#pragma unroll
    for (int k = 0; k < KN; k++) {
      const float4* Nrow = (const float4*)(S + (size_t)ix[k] * DN);
      float4 n0 = Nrow[lane];
      float4 n1 = Nrow[lane + 64];
      float wk = w[k];
      m0.x = fmaf(wk, n0.x, m0.x); m0.y = fmaf(wk, n0.y, m0.y);
      m0.z = fmaf(wk, n0.z, m0.z); m0.w = fmaf(wk, n0.w, m0.w);
      m1.x = fmaf(wk, n1.x, m1.x); m1.y = fmaf(wk, n1.y, m1.y);
      m1.z = fmaf(wk, n1.z, m1.z); m1.w = fmaf(wk, n1.w, m1.w);
    }

    float dot = s0.x * m0.x + s0.y * m0.y + s0.z * m0.z + s0.w * m0.w
              + s1.x * m1.x + s1.y * m1.y + s1.z * m1.z + s1.w * m1.w;
    float ns  = s0.x * s0.x + s0.y * s0.y + s0.z * s0.z + s0.w * s0.w
              + s1.x * s1.x + s1.y * s1.y + s1.z * s1.z + s1.w * s1.w;
    float nm  = m0.x * m0.x + m0.y * m0.y + m0.z * m0.z + m0.w * m0.w
              + m1.x * m1.x + m1.y * m1.y + m1.z * m1.z + m1.w * m1.w;

#pragma unroll
    for (int off = 32; off > 0; off >>= 1) {
      dot += __shfl_down(dot, off, 64);
      ns  += __shfl_down(ns,  off, 64);
      nm  += __shfl_down(nm,  off, 64);
    }
    if (lane == 0) {
      wavesim += dot / ((1e-10f + sqrtf(ns)) * (1e-10f + sqrtf(nm)));
    }
  }

  // contention-free tail: one store per block
  __shared__ float psim[8];
  if (lane == 0) psim[wv] = wavesim;
  __syncthreads();
  if (tid == 0) {
    float s = 0.0f;
#pragma unroll
    for (int i = 0; i < 8; i++) s += psim[i];
    partials[blk] = s;
  }
  grid.sync();

  // ---- P6: block 0 reduces 256 partials -> out ----
  if (blk == 0) {
    float s = (tid < 256) ? partials[tid] : 0.0f;
#pragma unroll
    for (int off = 32; off > 0; off >>= 1) s += __shfl_down(s, off, 64);
    __shared__ float ps[8];
    if (lane == 0) ps[wv] = s;
    __syncthreads();
    if (tid == 0) {
      float tot = 0.0f;
#pragma unroll
      for (int i = 0; i < 8; i++) tot += ps[i];
      out[0] = 1.0f - tot * (1.0f / (float)BN);
    }
  }
}

extern "C" void kernel_launch(void* const* d_in, const int* in_sizes, int n_in,
                              void* d_out, int out_size, void* d_ws, size_t ws_size,
                              hipStream_t stream) {
  const float* S = (const float*)d_in[0];  // Struct (8192 x 512) fp32
  const float* L = (const float*)d_in[1];  // Label  (8192)       fp32
  float* out = (float*)d_out;

  char* ws = (char*)d_ws;
  u64*   keys0     = (u64*)  (ws + OFF_K0);
  u64*   keys1     = (u64*)  (ws + OFF_K1);
  int*   sortedIdx = (int*)  (ws + OFF_SIDX);
  float* sortedLab = (float*)(ws + OFF_SLAB);
  float* partials  = (float*)(ws + OFF_PART);

  void* args[] = { (void*)&S, (void*)&L, (void*)&keys0, (void*)&keys1,
                   (void*)&sortedIdx, (void*)&sortedLab, (void*)&partials,
                   (void*)&out };
  hipLaunchCooperativeKernel((const void*)fused_kernel, dim3(256), dim3(512),
                             args, 0, stream);
}

// Round 7
// 93.653 us; speedup vs baseline: 2.3392x; 2.3392x over previous
//
#include <hip/hip_runtime.h>
#include <math.h>

#define BN 8192
#define DN 512
#define KN 8
#define WIN 16          // window half-width around sorted rank (>= KN, margin for ties)

typedef unsigned long long u64;
typedef unsigned int u32;

// ---- ws layout (bytes) ----
// keys0     : u64  [8192] @ 0       (after merge2: two sorted 4096-runs)
// keys1     : u64  [8192] @ 65536
// partials  : float[512]  @ 131072
#define OFF_K0    0
#define OFF_K1    65536
#define OFF_PART  131072

// Order-preserving float->uint transform (all floats).
__device__ __forceinline__ u32 flip_f32(u32 f) {
  return f ^ (u32)(((int)f >> 31) | 0x80000000);
}
__device__ __forceinline__ float unflip_f32(u32 f) {
  return __uint_as_float((f & 0x80000000u) ? (f ^ 0x80000000u) : ~f);
}

__device__ __forceinline__ u64 shfl_xor_u64(u64 v, int mask) {
  u32 lo = (u32)v, hi = (u32)(v >> 32);
  lo = (u32)__shfl_xor((int)lo, mask, 64);
  hi = (u32)__shfl_xor((int)hi, mask, 64);
  return ((u64)hi << 32) | lo;
}

// Merge-path level inside LDS: in has sorted runs of length R (power of 2),
// out gets runs of 2R. 1024 elements, 512 threads -> 2 outputs/thread.
__device__ __forceinline__ void lds_merge(const u64* in, u64* out, int R, int tid) {
  for (int o = tid; o < 1024; o += 512) {
    int off = o & (2 * R - 1);
    const u64* A = in + (o - off);
    const u64* B = A + R;
    int lo = off > R ? off - R : 0;
    int hi = off < R ? off : R;
    while (lo < hi) {
      int m = (lo + hi) >> 1;
      if (A[m] < B[off - m - 1]) lo = m + 1; else hi = m;
    }
    int a = lo, b = off - lo;
    u64 va = (a < R) ? A[a] : ~0ull;
    u64 vb = (b < R) ? B[b] : ~0ull;
    out[o] = va < vb ? va : vb;
  }
}

// ---------------------------------------------------------------------------
// Kernel A (proven R5): 8 blocks x 512 threads -> eight sorted 1024-runs.
// ---------------------------------------------------------------------------
__global__ __launch_bounds__(512) void sort1_kernel(const float* __restrict__ L,
                                                    u64* __restrict__ keys) {
  __shared__ u64 bufA[1024];
  __shared__ u64 bufB[1024];
  const int tid  = threadIdx.x;
  const int lane = tid & 63;
  const int wv   = tid >> 6;                       // 0..7
  const int base = blockIdx.x * 1024 + wv * 128;

  const int g0 = base + lane, g1 = base + 64 + lane;
  u64 v0 = ((u64)flip_f32(__float_as_uint(L[g0])) << 32) | (u32)g0;
  u64 v1 = ((u64)flip_f32(__float_as_uint(L[g1])) << 32) | (u32)g1;

#pragma unroll
  for (int k = 2; k <= 128; k <<= 1) {
#pragma unroll
    for (int j = 64; j > 0; j >>= 1) {
      if (j >= k) continue;
      if (j == 64) {                               // k==128: cross-reg, ascending
        u64 mn = v0 < v1 ? v0 : v1;
        u64 mx = v0 < v1 ? v1 : v0;
        v0 = mn; v1 = mx;
      } else {
        u64 o0 = shfl_xor_u64(v0, j);
        u64 o1 = shfl_xor_u64(v1, j);
        bool lower = (lane & j) == 0;
        bool up0, up1;
        if (k == 128)     { up0 = true;  up1 = true;  }
        else if (k == 64) { up0 = true;  up1 = false; }
        else { bool u = (lane & k) == 0; up0 = u; up1 = u; }
        bool t0 = (up0 == lower), t1 = (up1 == lower);
        v0 = t0 ? (v0 < o0 ? v0 : o0) : (v0 < o0 ? o0 : v0);
        v1 = t1 ? (v1 < o1 ? v1 : o1) : (v1 < o1 ? o1 : v1);
      }
    }
  }

  bufA[wv * 128 + lane]      = v0;
  bufA[wv * 128 + 64 + lane] = v1;
  __syncthreads();
  lds_merge(bufA, bufB, 128, tid); __syncthreads();
  lds_merge(bufB, bufA, 256, tid); __syncthreads();
  lds_merge(bufA, bufB, 512, tid); __syncthreads();

  keys[blockIdx.x * 1024 + tid]       = bufB[tid];
  keys[blockIdx.x * 1024 + 512 + tid] = bufB[512 + tid];
}

// ---------------------------------------------------------------------------
// Kernel B (proven R5): global merge-path pass, runs RUN -> 2*RUN.
// ---------------------------------------------------------------------------
template <int RUN>
__global__ __launch_bounds__(256) void merge_pass_kernel(const u64* __restrict__ in,
                                                         u64* __restrict__ outk) {
  const int t = blockIdx.x * 256 + threadIdx.x;   // 0..8191
  const int seg = t / (2 * RUN);
  const int o   = t & (2 * RUN - 1);
  const u64* A = in + seg * 2 * RUN;
  const u64* B = A + RUN;

  int lo = (o > RUN) ? (o - RUN) : 0;
  int hi = (o < RUN) ? o : RUN;
  while (lo < hi) {
    int a = (lo + hi) >> 1;
    if (A[a] < B[o - a - 1]) lo = a + 1; else hi = a;
  }
  const int a = lo, b = o - a;
  u64 va = (a < RUN) ? A[a] : ~0ull;
  u64 vb = (b < RUN) ? B[b] : ~0ull;
  outk[t] = (va < vb) ? va : vb;
}

// ---------------------------------------------------------------------------
// Kernel C: 512 blocks x 256 threads, 16 consecutive sorted ranks per block
// (XCD-swizzled spans). The block reconstructs its 48-rank window from the
// two 4096-runs via merge-path co-rank search (fused final merge pass), then
// each wave runs the proven selection bitonic + gather + cosine for 4 rows.
// Contention-free tail: one partials store per block.
// ---------------------------------------------------------------------------
__global__ __launch_bounds__(256) void wmean_cos_kernel(const float* __restrict__ S,
                                                        const u64* __restrict__ keys,
                                                        float* __restrict__ partials) {
  const int tid  = threadIdx.x;
  const int lane = tid & 63;
  const int wv   = tid >> 6;                 // 0..3
  const int blk  = blockIdx.x;               // 0..511
  const int xcd  = blk & 7;
  const int span = blk >> 3;                 // 0..63
  const int base = xcd * 1024 + span * 16;   // first row-rank of this block

  __shared__ u64 win[48];                    // ranks base-16 .. base+31

  if (tid < 48) {
    int q = base - WIN + tid;
    u64 v = ~0ull;
    if (q >= 0 && q < BN) {
      const u64* A = keys;
      const u64* B = keys + 4096;
      int lo = (q > 4096) ? (q - 4096) : 0;
      int hi = (q < 4096) ? q : 4096;
      while (lo < hi) {
        int a = (lo + hi) >> 1;
        if (A[a] < B[q - a - 1]) lo = a + 1; else hi = a;
      }
      int a = lo, b = q - lo;
      u64 va = (a < 4096) ? A[a] : ~0ull;
      u64 vb = (b < 4096) ? B[b] : ~0ull;
      v = (va < vb) ? va : vb;
    }
    win[tid] = v;
  }
  __syncthreads();

  float wavesim = 0.0f;

  for (int r = 0; r < 4; ++r) {
    const int rw = wv * 4 + r;               // 0..15: row's offset in block span
    const u64 ckey = win[rw + WIN];          // center rank (always valid)
    const float Lb = unflip_f32((u32)(ckey >> 32));
    const int   b  = (int)(u32)ckey;

    // candidates: window indices rw .. rw+32 on lanes 0..32
    u64 key = ~0ull;
    if (lane <= 2 * WIN) {
      u64 k = win[rw + lane];
      if (k != ~0ull) {                      // real keys never equal ~0ull (idx<8192)
        float lab = unflip_f32((u32)(k >> 32));
        float dist = fabsf(lab - Lb);        // >=0: IEEE bits order-preserving
        key = ((u64)__float_as_uint(dist) << 32) | (u32)k;
      }
    }
    // 64-lane bitonic sort ascending (21 substeps)
#pragma unroll
    for (int k = 2; k <= 64; k <<= 1) {
#pragma unroll
      for (int j = 32; j > 0; j >>= 1) {
        if (j >= k) continue;
        u64 o = shfl_xor_u64(key, j);
        bool lower = (lane & j) == 0;
        bool up = (k == 64) ? true : ((lane & k) == 0);
        key = (up == lower) ? (key < o ? key : o) : (key < o ? o : key);
      }
    }
    // lanes 0..7 hold the 8 nearest; normalized Gaussian weights
    float e = 0.0f;
    if (lane < 8) {
      float d = __uint_as_float((u32)(key >> 32));
      e = expf(-d * d * (1.0f / 50.0f));     // 2*STD^2 = 50; const cancels
    }
    float ssum = e;
    ssum += __shfl_xor(ssum, 1, 64);
    ssum += __shfl_xor(ssum, 2, 64);
    ssum += __shfl_xor(ssum, 4, 64);
    float wn = e / ssum;

    int ix[KN]; float w[KN];
    int myidx = (int)(u32)key;
#pragma unroll
    for (int k = 0; k < KN; k++) {
      ix[k] = __shfl(myidx, k, 64);
      w[k]  = __shfl(wn,    k, 64);
    }

    // gather + weighted mean + cosine
    const float4* Srow = (const float4*)(S + (size_t)b * DN);
    float4 s0 = Srow[lane];
    float4 s1 = Srow[lane + 64];

    float4 m0 = make_float4(0.f, 0.f, 0.f, 0.f);
    float4 m1 = make_float4(0.f, 0.f, 0.f, 0.f);
#pragma unroll
    for (int k = 0; k < KN; k++) {
      const float4* Nrow = (const float4*)(S + (size_t)ix[k] * DN);
      float4 n0 = Nrow[lane];
      float4 n1 = Nrow[lane + 64];
      float wk = w[k];
      m0.x = fmaf(wk, n0.x, m0.x); m0.y = fmaf(wk, n0.y, m0.y);
      m0.z = fmaf(wk, n0.z, m0.z); m0.w = fmaf(wk, n0.w, m0.w);
      m1.x = fmaf(wk, n1.x, m1.x); m1.y = fmaf(wk, n1.y, m1.y);
      m1.z = fmaf(wk, n1.z, m1.z); m1.w = fmaf(wk, n1.w, m1.w);
    }

    float dot = s0.x * m0.x + s0.y * m0.y + s0.z * m0.z + s0.w * m0.w
              + s1.x * m1.x + s1.y * m1.y + s1.z * m1.z + s1.w * m1.w;
    float ns  = s0.x * s0.x + s0.y * s0.y + s0.z * s0.z + s0.w * s0.w
              + s1.x * s1.x + s1.y * s1.y + s1.z * s1.z + s1.w * s1.w;
    float nm  = m0.x * m0.x + m0.y * m0.y + m0.z * m0.z + m0.w * m0.w
              + m1.x * m1.x + m1.y * m1.y + m1.z * m1.z + m1.w * m1.w;

#pragma unroll
    for (int off = 32; off > 0; off >>= 1) {
      dot += __shfl_down(dot, off, 64);
      ns  += __shfl_down(ns,  off, 64);
      nm  += __shfl_down(nm,  off, 64);
    }
    if (lane == 0) {
      wavesim += dot / ((1e-10f + sqrtf(ns)) * (1e-10f + sqrtf(nm)));
    }
  }

  __shared__ float psim[4];
  if (lane == 0) psim[wv] = wavesim;
  __syncthreads();
  if (tid == 0) {
    partials[blk] = psim[0] + psim[1] + psim[2] + psim[3];
  }
}

// ---------------------------------------------------------------------------
// Kernel D: reduce 512 partials -> out[0] = 1 - sum/8192.
// ---------------------------------------------------------------------------
__global__ __launch_bounds__(256) void finalize_kernel(const float* __restrict__ partials,
                                                       float* __restrict__ out) {
  const int tid = threadIdx.x;
  float s = 0.0f;
  for (int i = tid; i < 512; i += 256) s += partials[i];
#pragma unroll
  for (int off = 32; off > 0; off >>= 1) s += __shfl_down(s, off, 64);
  __shared__ float ps[4];
  if ((tid & 63) == 0) ps[tid >> 6] = s;
  __syncthreads();
  if (tid == 0) {
    float tot = ps[0] + ps[1] + ps[2] + ps[3];
    out[0] = 1.0f - tot * (1.0f / (float)BN);
  }
}

extern "C" void kernel_launch(void* const* d_in, const int* in_sizes, int n_in,
                              void* d_out, int out_size, void* d_ws, size_t ws_size,
                              hipStream_t stream) {
  const float* S = (const float*)d_in[0];  // Struct (8192 x 512) fp32
  const float* L = (const float*)d_in[1];  // Label  (8192)       fp32
  float* out = (float*)d_out;

  char* ws = (char*)d_ws;
  u64*   keys0    = (u64*)  (ws + OFF_K0);
  u64*   keys1    = (u64*)  (ws + OFF_K1);
  float* partials = (float*)(ws + OFF_PART);

  sort1_kernel<<<8, 512, 0, stream>>>(L, keys0);
  merge_pass_kernel<1024><<<32, 256, 0, stream>>>(keys0, keys1);
  merge_pass_kernel<2048><<<32, 256, 0, stream>>>(keys1, keys0);
  wmean_cos_kernel<<<512, 256, 0, stream>>>(S, keys0, partials);
  finalize_kernel <<<1, 256, 0, stream>>>(partials, out);
}

// Round 8
// 92.436 us; speedup vs baseline: 2.3700x; 1.0132x over previous
//
#include <hip/hip_runtime.h>
#include <math.h>

#define BN 8192
#define DN 512
#define KN 8
#define WIN 16          // window half-width around sorted rank (>= KN, margin for ties)

typedef unsigned long long u64;
typedef unsigned int u32;

// ---- ws layout (bytes) ----
// keys0     : u64  [8192] @ 0       (after merge2: two sorted 4096-runs)
// keys1     : u64  [8192] @ 65536
// partials  : float[2048] @ 131072
#define OFF_K0    0
#define OFF_K1    65536
#define OFF_PART  131072

// Order-preserving float->uint transform (all floats).
__device__ __forceinline__ u32 flip_f32(u32 f) {
  return f ^ (u32)(((int)f >> 31) | 0x80000000);
}
__device__ __forceinline__ float unflip_f32(u32 f) {
  return __uint_as_float((f & 0x80000000u) ? (f ^ 0x80000000u) : ~f);
}

__device__ __forceinline__ u64 shfl_xor_u64(u64 v, int mask) {
  u32 lo = (u32)v, hi = (u32)(v >> 32);
  lo = (u32)__shfl_xor((int)lo, mask, 64);
  hi = (u32)__shfl_xor((int)hi, mask, 64);
  return ((u64)hi << 32) | lo;
}

// Merge-path level inside LDS: in has sorted runs of length R (power of 2),
// out gets runs of 2R. 1024 elements, 512 threads -> 2 outputs/thread.
__device__ __forceinline__ void lds_merge(const u64* in, u64* out, int R, int tid) {
  for (int o = tid; o < 1024; o += 512) {
    int off = o & (2 * R - 1);
    const u64* A = in + (o - off);
    const u64* B = A + R;
    int lo = off > R ? off - R : 0;
    int hi = off < R ? off : R;
    while (lo < hi) {
      int m = (lo + hi) >> 1;
      if (A[m] < B[off - m - 1]) lo = m + 1; else hi = m;
    }
    int a = lo, b = off - lo;
    u64 va = (a < R) ? A[a] : ~0ull;
    u64 vb = (b < R) ? B[b] : ~0ull;
    out[o] = va < vb ? va : vb;
  }
}

// ---------------------------------------------------------------------------
// Kernel A (proven R5): 8 blocks x 512 threads -> eight sorted 1024-runs.
// ---------------------------------------------------------------------------
__global__ __launch_bounds__(512) void sort1_kernel(const float* __restrict__ L,
                                                    u64* __restrict__ keys) {
  __shared__ u64 bufA[1024];
  __shared__ u64 bufB[1024];
  const int tid  = threadIdx.x;
  const int lane = tid & 63;
  const int wv   = tid >> 6;                       // 0..7
  const int base = blockIdx.x * 1024 + wv * 128;

  const int g0 = base + lane, g1 = base + 64 + lane;
  u64 v0 = ((u64)flip_f32(__float_as_uint(L[g0])) << 32) | (u32)g0;
  u64 v1 = ((u64)flip_f32(__float_as_uint(L[g1])) << 32) | (u32)g1;

#pragma unroll
  for (int k = 2; k <= 128; k <<= 1) {
#pragma unroll
    for (int j = 64; j > 0; j >>= 1) {
      if (j >= k) continue;
      if (j == 64) {                               // k==128: cross-reg, ascending
        u64 mn = v0 < v1 ? v0 : v1;
        u64 mx = v0 < v1 ? v1 : v0;
        v0 = mn; v1 = mx;
      } else {
        u64 o0 = shfl_xor_u64(v0, j);
        u64 o1 = shfl_xor_u64(v1, j);
        bool lower = (lane & j) == 0;
        bool up0, up1;
        if (k == 128)     { up0 = true;  up1 = true;  }
        else if (k == 64) { up0 = true;  up1 = false; }
        else { bool u = (lane & k) == 0; up0 = u; up1 = u; }
        bool t0 = (up0 == lower), t1 = (up1 == lower);
        v0 = t0 ? (v0 < o0 ? v0 : o0) : (v0 < o0 ? o0 : v0);
        v1 = t1 ? (v1 < o1 ? v1 : o1) : (v1 < o1 ? o1 : v1);
      }
    }
  }

  bufA[wv * 128 + lane]      = v0;
  bufA[wv * 128 + 64 + lane] = v1;
  __syncthreads();
  lds_merge(bufA, bufB, 128, tid); __syncthreads();
  lds_merge(bufB, bufA, 256, tid); __syncthreads();
  lds_merge(bufA, bufB, 512, tid); __syncthreads();

  keys[blockIdx.x * 1024 + tid]       = bufB[tid];
  keys[blockIdx.x * 1024 + 512 + tid] = bufB[512 + tid];
}

// ---------------------------------------------------------------------------
// Kernel B (proven R5): global merge-path pass, runs RUN -> 2*RUN.
// ---------------------------------------------------------------------------
template <int RUN>
__global__ __launch_bounds__(256) void merge_pass_kernel(const u64* __restrict__ in,
                                                         u64* __restrict__ outk) {
  const int t = blockIdx.x * 256 + threadIdx.x;   // 0..8191
  const int seg = t / (2 * RUN);
  const int o   = t & (2 * RUN - 1);
  const u64* A = in + seg * 2 * RUN;
  const u64* B = A + RUN;

  int lo = (o > RUN) ? (o - RUN) : 0;
  int hi = (o < RUN) ? o : RUN;
  while (lo < hi) {
    int a = (lo + hi) >> 1;
    if (A[a] < B[o - a - 1]) lo = a + 1; else hi = a;
  }
  const int a = lo, b = o - a;
  u64 va = (a < RUN) ? A[a] : ~0ull;
  u64 vb = (b < RUN) ? B[b] : ~0ull;
  outk[t] = (va < vb) ? va : vb;
}

// ---------------------------------------------------------------------------
// Kernel C: 2048 blocks x 256 threads, 4 consecutive sorted ranks per block
// (one row per wave; 8 blocks/CU -> 32 waves/CU for latency hiding).
// Block reconstructs its 36-rank window from the two 4096-runs via merge-path
// co-rank search (fused final merge pass), then each wave runs the proven
// selection bitonic + gather + cosine for its row.
// Contention-free tail: one partials store per block.
// ---------------------------------------------------------------------------
__global__ __launch_bounds__(256) void wmean_cos_kernel(const float* __restrict__ S,
                                                        const u64* __restrict__ keys,
                                                        float* __restrict__ partials) {
  const int tid  = threadIdx.x;
  const int lane = tid & 63;
  const int wv   = tid >> 6;                 // 0..3
  const int blk  = blockIdx.x;               // 0..2047
  const int xcd  = blk & 7;
  const int span = blk >> 3;                 // 0..255
  const int base = xcd * 1024 + span * 4;    // first row-rank of this block

  __shared__ u64 win[4 + 2 * WIN];           // ranks base-16 .. base+19 (36)

  if (tid < 4 + 2 * WIN) {
    int q = base - WIN + tid;
    u64 v = ~0ull;
    if (q >= 0 && q < BN) {
      const u64* A = keys;
      const u64* B = keys + 4096;
      int lo = (q > 4096) ? (q - 4096) : 0;
      int hi = (q < 4096) ? q : 4096;
      while (lo < hi) {
        int a = (lo + hi) >> 1;
        if (A[a] < B[q - a - 1]) lo = a + 1; else hi = a;
      }
      int a = lo, b = q - lo;
      u64 va = (a < 4096) ? A[a] : ~0ull;
      u64 vb = (b < 4096) ? B[b] : ~0ull;
      v = (va < vb) ? va : vb;
    }
    win[tid] = v;
  }
  __syncthreads();

  const int rw = wv;                         // row offset within block span
  const u64 ckey = win[rw + WIN];            // center rank (always valid)
  const float Lb = unflip_f32((u32)(ckey >> 32));
  const int   b  = (int)(u32)ckey;

  // candidates: window indices rw .. rw+32 on lanes 0..32
  u64 key = ~0ull;
  if (lane <= 2 * WIN) {
    u64 k = win[rw + lane];
    if (k != ~0ull) {                        // real keys never equal ~0ull (idx<8192)
      float lab = unflip_f32((u32)(k >> 32));
      float dist = fabsf(lab - Lb);          // >=0: IEEE bits order-preserving
      key = ((u64)__float_as_uint(dist) << 32) | (u32)k;
    }
  }
  // 64-lane bitonic sort ascending (21 substeps)
#pragma unroll
  for (int k = 2; k <= 64; k <<= 1) {
#pragma unroll
    for (int j = 32; j > 0; j >>= 1) {
      if (j >= k) continue;
      u64 o = shfl_xor_u64(key, j);
      bool lower = (lane & j) == 0;
      bool up = (k == 64) ? true : ((lane & k) == 0);
      key = (up == lower) ? (key < o ? key : o) : (key < o ? o : key);
    }
  }
  // lanes 0..7 hold the 8 nearest; normalized Gaussian weights
  float e = 0.0f;
  if (lane < 8) {
    float d = __uint_as_float((u32)(key >> 32));
    e = expf(-d * d * (1.0f / 50.0f));       // 2*STD^2 = 50; const cancels
  }
  float ssum = e;
  ssum += __shfl_xor(ssum, 1, 64);
  ssum += __shfl_xor(ssum, 2, 64);
  ssum += __shfl_xor(ssum, 4, 64);
  float wn = e / ssum;

  int ix[KN]; float w[KN];
  int myidx = (int)(u32)key;
#pragma unroll
  for (int k = 0; k < KN; k++) {
    ix[k] = __shfl(myidx, k, 64);
    w[k]  = __shfl(wn,    k, 64);
  }

  // gather + weighted mean + cosine
  const float4* Srow = (const float4*)(S + (size_t)b * DN);
  float4 s0 = Srow[lane];
  float4 s1 = Srow[lane + 64];

  float4 m0 = make_float4(0.f, 0.f, 0.f, 0.f);
  float4 m1 = make_float4(0.f, 0.f, 0.f, 0.f);
#pragma unroll
  for (int k = 0; k < KN; k++) {
    const float4* Nrow = (const float4*)(S + (size_t)ix[k] * DN);
    float4 n0 = Nrow[lane];
    float4 n1 = Nrow[lane + 64];
    float wk = w[k];
    m0.x = fmaf(wk, n0.x, m0.x); m0.y = fmaf(wk, n0.y, m0.y);
    m0.z = fmaf(wk, n0.z, m0.z); m0.w = fmaf(wk, n0.w, m0.w);
    m1.x = fmaf(wk, n1.x, m1.x); m1.y = fmaf(wk, n1.y, m1.y);
    m1.z = fmaf(wk, n1.z, m1.z); m1.w = fmaf(wk, n1.w, m1.w);
  }

  float dot = s0.x * m0.x + s0.y * m0.y + s0.z * m0.z + s0.w * m0.w
            + s1.x * m1.x + s1.y * m1.y + s1.z * m1.z + s1.w * m1.w;
  float ns  = s0.x * s0.x + s0.y * s0.y + s0.z * s0.z + s0.w * s0.w
            + s1.x * s1.x + s1.y * s1.y + s1.z * s1.z + s1.w * s1.w;
  float nm  = m0.x * m0.x + m0.y * m0.y + m0.z * m0.z + m0.w * m0.w
            + m1.x * m1.x + m1.y * m1.y + m1.z * m1.z + m1.w * m1.w;

#pragma unroll
  for (int off = 32; off > 0; off >>= 1) {
    dot += __shfl_down(dot, off, 64);
    ns  += __shfl_down(ns,  off, 64);
    nm  += __shfl_down(nm,  off, 64);
  }

  __shared__ float psim[4];
  if (lane == 0) {
    psim[wv] = dot / ((1e-10f + sqrtf(ns)) * (1e-10f + sqrtf(nm)));
  }
  __syncthreads();
  if (tid == 0) {
    partials[blk] = psim[0] + psim[1] + psim[2] + psim[3];
  }
}

// ---------------------------------------------------------------------------
// Kernel D: reduce 2048 partials -> out[0] = 1 - sum/8192.
// ---------------------------------------------------------------------------
__global__ __launch_bounds__(256) void finalize_kernel(const float* __restrict__ partials,
                                                       float* __restrict__ out) {
  const int tid = threadIdx.x;
  float s = 0.0f;
  for (int i = tid; i < 2048; i += 256) s += partials[i];
#pragma unroll
  for (int off = 32; off > 0; off >>= 1) s += __shfl_down(s, off, 64);
  __shared__ float ps[4];
  if ((tid & 63) == 0) ps[tid >> 6] = s;
  __syncthreads();
  if (tid == 0) {
    float tot = ps[0] + ps[1] + ps[2] + ps[3];
    out[0] = 1.0f - tot * (1.0f / (float)BN);
  }
}

extern "C" void kernel_launch(void* const* d_in, const int* in_sizes, int n_in,
                              void* d_out, int out_size, void* d_ws, size_t ws_size,
                              hipStream_t stream) {
  const float* S = (const float*)d_in[0];  // Struct (8192 x 512) fp32
  const float* L = (const float*)d_in[1];  // Label  (8192)       fp32
  float* out = (float*)d_out;

  char* ws = (char*)d_ws;
  u64*   keys0    = (u64*)  (ws + OFF_K0);
  u64*   keys1    = (u64*)  (ws + OFF_K1);
  float* partials = (float*)(ws + OFF_PART);

  sort1_kernel<<<8, 512, 0, stream>>>(L, keys0);
  merge_pass_kernel<1024><<<32, 256, 0, stream>>>(keys0, keys1);
  merge_pass_kernel<2048><<<32, 256, 0, stream>>>(keys1, keys0);
  wmean_cos_kernel<<<2048, 256, 0, stream>>>(S, keys0, partials);
  finalize_kernel <<<1, 256, 0, stream>>>(partials, out);
}